// Round 5
// baseline (151.035 us; speedup 1.0000x reference)
//
#include <hip/hip_runtime.h>
#include <hip/hip_bf16.h>

#define N_ROWS 8192
#define H_DIM  1024
#define NUM_CLS 64
#define BT 256                          // tile: 256x256
#define BK 64                           // K per tile-step
#define NT (H_DIM / BK)                 // 16 K-tiles
#define NP (N_ROWS / BT)                // 32 panels
#define NOFF (NP * (NP - 1) / 2)        // 496 off-diagonal pairs
#define NPAIR (NOFF + NP)               // 528 blocks

typedef __bf16 bf16x8 __attribute__((ext_vector_type(8)));
typedef float  f32x4  __attribute__((ext_vector_type(4)));

__device__ __forceinline__ float fast_exp2(float x) {
    float r;
    asm("v_exp_f32 %0, %1" : "=v"(r) : "v"(x));
    return r;
}

__device__ __forceinline__ void async_copy16(void* lds, const void* g) {
    __builtin_amdgcn_global_load_lds(
        (const __attribute__((address_space(1))) void*)g,
        (__attribute__((address_space(3))) void*)lds, 16, 0, 0);
}

// ---------------- Kernel 1: row-normalize fp32 -> bf16 ----------------
__global__ __launch_bounds__(256) void norm_kernel(const float* __restrict__ in,
                                                   ushort* __restrict__ out) {
    const int row = blockIdx.x, tid = threadIdx.x;
    const float4 v = reinterpret_cast<const float4*>(in + (size_t)row * H_DIM)[tid];
    float ss = v.x * v.x + v.y * v.y + v.z * v.z + v.w * v.w;
#pragma unroll
    for (int d = 1; d < 64; d <<= 1) ss += __shfl_xor(ss, d, 64);
    __shared__ float sred[4];
    const int lane = tid & 63, wid = tid >> 6;
    if (lane == 0) sred[wid] = ss;
    __syncthreads();
    const float tot = sred[0] + sred[1] + sred[2] + sred[3];
    const float inv = 1.0f / fmaxf(sqrtf(tot), 1e-12f);
    __hip_bfloat16 o0 = __float2bfloat16(v.x * inv);
    __hip_bfloat16 o1 = __float2bfloat16(v.y * inv);
    __hip_bfloat16 o2 = __float2bfloat16(v.z * inv);
    __hip_bfloat16 o3 = __float2bfloat16(v.w * inv);
    ushort4 o;
    o.x = *reinterpret_cast<ushort*>(&o0);
    o.y = *reinterpret_cast<ushort*>(&o1);
    o.z = *reinterpret_cast<ushort*>(&o2);
    o.w = *reinterpret_cast<ushort*>(&o3);
    reinterpret_cast<ushort4*>(out + (size_t)row * H_DIM)[tid] = o;
}

// ---- Kernel 2: symmetric fused Gram + exp + masked row/col partials ----
// 256x256 tile, 512 thr (8 waves 2Mx4N). BK=64, 2-slot dbuf (128 KB),
// 4 phases/K-tile {ds_read quad frags; BAR; setprio+16 MFMA; BAR}, stages of
// tile t+1 go to the DEAD slot right after the boundary barrier (race-free),
// boundary vmcnt(0)+barrier. Diagonal blocks skip strictly-lower quadrants.
__global__ __launch_bounds__(512, 2)
void simloss_kernel(const ushort* __restrict__ xb, const int* __restrict__ labels,
                    float* __restrict__ ppos, float* __restrict__ pall) {
    // [slot][chunk: A0,A1,B0,B1][128 rows x 64 cols bf16]: 2*4*16KB = 128 KB
    __shared__ __align__(16) ushort SL[2 * 4 * 8192];

    // LPT order: 496 off-diag pairs first, 32 half-weight diag blocks last
    int I, J;
    if ((int)blockIdx.x < NOFF) {
        int t = blockIdx.x, i = 0;
        while (t >= NP - 1 - i) { t -= NP - 1 - i; ++i; }
        I = i; J = i + 1 + t;
    } else {
        I = J = blockIdx.x - NOFF;
    }
    const bool diag = (I == J);
    const int row0 = I * BT, col0 = J * BT;

    const int tid  = threadIdx.x;
    const int lane = tid & 63;
    const int wid  = tid >> 6;        // 0..7
    const int wm = wid >> 2;          // 0..1  (M wave row)
    const int wn = wid & 3;           // 0..3  (N wave col)
    const int l15 = lane & 15, lq = lane >> 4;
    const int l7 = l15 & 7;

    // fragment read addressing (ushort units), physical slot = logical ^ (row&7)
    const int psw0 = (lq ^ l7) * 8;
    const int psw1 = ((4 + lq) ^ l7) * 8;
    const int aBase = wm * 8192 + l15 * 64;                       // chunk A{wm}
    const int bBase = (2 + (wn >> 1)) * 8192 + (wn & 1) * 4096 + l15 * 64;

    // diag quadrant skip: quadrant (qi,qj) strictly below diagonal iff
    // (2*wn+qj) < 2*(2*wm+qi)   [64-row band a vs 32-col band b: b < 2a]
    const bool sk00 = diag && (2 * wn     < 2 * (2 * wm));
    const bool sk01 = diag && (2 * wn + 1 < 2 * (2 * wm));
    const bool sk10 = diag && (2 * wn     < 2 * (2 * wm + 1));
    const bool sk11 = diag && (2 * wn + 1 < 2 * (2 * wm + 1));
    const bool ndA0 = !(sk00 && sk01), ndA1 = !(sk10 && sk11);
    const bool ndB0 = !(sk00 && sk10), ndB1 = !(sk01 && sk11);

    // STAGE one 16KB chunk (16 segs x 1KB); 2 issues/thread; linear LDS dest
    // (wave-uniform base + lane*16), source column pre-swizzled (rule #21)
#define STAGE_CHUNK(slot, chunk, grow0, k0)                                    \
    do {                                                                       \
        _Pragma("unroll")                                                      \
        for (int q = 0; q < 2; ++q) {                                          \
            const int seg = wid * 2 + q;                                       \
            const int row = seg * 8 + (lane >> 3);                             \
            const int ls  = (lane & 7) ^ (row & 7);                            \
            async_copy16(&SL[(slot) * 32768 + (chunk) * 8192 + seg * 512],     \
                         &xb[(size_t)((grow0) + row) * H_DIM + (k0) + ls * 8]);\
        }                                                                      \
    } while (0)

#define STAGE_TILE(slot, kt)                                                   \
    do {                                                                       \
        STAGE_CHUNK(slot, 0, row0,       (kt) * BK);                           \
        STAGE_CHUNK(slot, 1, row0 + 128, (kt) * BK);                           \
        STAGE_CHUNK(slot, 2, col0,       (kt) * BK);                           \
        STAGE_CHUNK(slot, 3, col0 + 128, (kt) * BK);                           \
    } while (0)

#define MFMA_Q(AF, BF, MO, NO)                                                 \
    do {                                                                       \
        __builtin_amdgcn_s_setprio(1);                                         \
        _Pragma("unroll")                                                      \
        for (int kh = 0; kh < 2; ++kh)                                         \
            _Pragma("unroll")                                                  \
            for (int i = 0; i < 4; ++i)                                        \
                _Pragma("unroll")                                              \
                for (int j = 0; j < 2; ++j)                                    \
                    acc[(MO) + i][(NO) + j] =                                  \
                        __builtin_amdgcn_mfma_f32_16x16x32_bf16(               \
                            AF[kh][i], BF[kh][j], acc[(MO) + i][(NO) + j],     \
                            0, 0, 0);                                          \
        __builtin_amdgcn_s_setprio(0);                                         \
    } while (0)

    f32x4 acc[8][4];
#pragma unroll
    for (int m = 0; m < 8; ++m)
#pragma unroll
        for (int n = 0; n < 4; ++n) acc[m][n] = (f32x4){0.f, 0.f, 0.f, 0.f};

    bf16x8 af[2][4], bf0[2][2], bf1[2][2];

    // prologue: stage tile 0 -> slot 0 (one-time full-latency drain)
    STAGE_TILE(0, 0);
    asm volatile("s_waitcnt vmcnt(0)" ::: "memory");
    __builtin_amdgcn_s_barrier();
    asm volatile("" ::: "memory");

    for (int t = 0; t < NT; ++t) {
        const int s = t & 1;
        const int sb = s * 32768;
        if (t + 1 < NT) STAGE_TILE(s ^ 1, t + 1);   // 8 issues -> dead slot

        // ---- phase 1: quadrant (0,0); reads A rows 0-63 + B cols 0-31
        if (ndA0) {
#pragma unroll
            for (int i = 0; i < 4; ++i) {
                af[0][i] = *reinterpret_cast<const bf16x8*>(&SL[sb + aBase + i * 1024 + psw0]);
                af[1][i] = *reinterpret_cast<const bf16x8*>(&SL[sb + aBase + i * 1024 + psw1]);
            }
        }
        if (ndB0) {
#pragma unroll
            for (int j = 0; j < 2; ++j) {
                bf0[0][j] = *reinterpret_cast<const bf16x8*>(&SL[sb + bBase + j * 1024 + psw0]);
                bf0[1][j] = *reinterpret_cast<const bf16x8*>(&SL[sb + bBase + j * 1024 + psw1]);
            }
        }
        __builtin_amdgcn_s_barrier();
        if (!sk00) MFMA_Q(af, bf0, 0, 0);
        __builtin_amdgcn_s_barrier();

        // ---- phase 2: quadrant (0,1); reads B cols 32-63
        if (ndB1) {
#pragma unroll
            for (int j = 0; j < 2; ++j) {
                bf1[0][j] = *reinterpret_cast<const bf16x8*>(&SL[sb + bBase + 2048 + j * 1024 + psw0]);
                bf1[1][j] = *reinterpret_cast<const bf16x8*>(&SL[sb + bBase + 2048 + j * 1024 + psw1]);
            }
        }
        __builtin_amdgcn_s_barrier();
        if (!sk01) MFMA_Q(af, bf1, 0, 2);
        __builtin_amdgcn_s_barrier();

        // ---- phase 3: quadrant (1,0); reads A rows 64-127
        if (ndA1) {
#pragma unroll
            for (int i = 0; i < 4; ++i) {
                af[0][i] = *reinterpret_cast<const bf16x8*>(&SL[sb + aBase + 4096 + i * 1024 + psw0]);
                af[1][i] = *reinterpret_cast<const bf16x8*>(&SL[sb + aBase + 4096 + i * 1024 + psw1]);
            }
        }
        __builtin_amdgcn_s_barrier();
        if (!sk10) MFMA_Q(af, bf0, 4, 0);
        __builtin_amdgcn_s_barrier();

        // ---- phase 4: quadrant (1,1); no reads
        if (!sk11) MFMA_Q(af, bf1, 4, 2);

        // boundary: tile t+1 resident (L2/L3-warm => tiny bubble)
        asm volatile("s_waitcnt vmcnt(0)" ::: "memory");
        __builtin_amdgcn_s_barrier();
        asm volatile("" ::: "memory");
    }
#undef STAGE_CHUNK
#undef STAGE_TILE
#undef MFMA_Q

    // ---- epilogue: exp + mask (colg > rowg) + row/col partial sums ----
    __syncthreads();
    int lab_c[4];
#pragma unroll
    for (int nf = 0; nf < 4; ++nf)
        lab_c[nf] = labels[col0 + wn * 64 + nf * 16 + l15];
    float cs_p[4] = {0.f, 0.f, 0.f, 0.f}, cs_a[4] = {0.f, 0.f, 0.f, 0.f};

    float* sc = (float*)&SL[0];
    float* rowpos = sc;            // [4][256] indexed [wn][localrow]
    float* rowall = sc + 1024;
    float* colpos = sc + 2048;     // [2][256] indexed [wm][localcol]
    float* colall = sc + 2560;

#pragma unroll
    for (int mf = 0; mf < 8; ++mf) {
#pragma unroll
        for (int r = 0; r < 4; ++r) {
            const int lrow = wm * 128 + mf * 16 + lq * 4 + r;
            const int rowg = row0 + lrow;
            const int labr = labels[rowg];
            float p = 0.f, a = 0.f;
#pragma unroll
            for (int nf = 0; nf < 4; ++nf) {
                const int colg = col0 + wn * 64 + nf * 16 + l15;
                const float e = fast_exp2(acc[mf][nf][r] * 14.4269504088896340736f);
                const bool use = (colg > rowg);   // strict upper; off-diag always
                const float ea = use ? e : 0.f;
                const float ep = (use && labr == lab_c[nf]) ? e : 0.f;
                a += ea; p += ep;
                cs_a[nf] += ea; cs_p[nf] += ep;
            }
#pragma unroll
            for (int d = 1; d < 16; d <<= 1) {
                p += __shfl_xor(p, d, 64);
                a += __shfl_xor(a, d, 64);
            }
            if (l15 == 0) {
                rowpos[wn * 256 + lrow] = p;
                rowall[wn * 256 + lrow] = a;
            }
        }
    }
#pragma unroll
    for (int nf = 0; nf < 4; ++nf) {
#pragma unroll
        for (int d = 16; d < 64; d <<= 1) {
            cs_p[nf] += __shfl_xor(cs_p[nf], d, 64);
            cs_a[nf] += __shfl_xor(cs_a[nf], d, 64);
        }
    }
    if (lq == 0) {
#pragma unroll
        for (int nf = 0; nf < 4; ++nf) {
            const int lcol = wn * 64 + nf * 16 + l15;
            colpos[wm * 256 + lcol] = cs_p[nf];
            colall[wm * 256 + lcol] = cs_a[nf];
        }
    }
    __syncthreads();

    // partial-slot scheme: row-side -> slot J, col-side -> slot I; diag folds
    // its (strict-upper) col sums into the row sums => complete in-panel sums.
    if (tid < 256) {
        float rp = rowpos[tid] + rowpos[256 + tid] + rowpos[512 + tid] + rowpos[768 + tid];
        float ra = rowall[tid] + rowall[256 + tid] + rowall[512 + tid] + rowall[768 + tid];
        if (diag) {
            rp += colpos[tid] + colpos[256 + tid];
            ra += colall[tid] + colall[256 + tid];
        }
        ppos[(size_t)J * N_ROWS + row0 + tid] = rp;
        pall[(size_t)J * N_ROWS + row0 + tid] = ra;
    } else if (!diag) {
        const int c = tid - 256;
        const float cp = colpos[c] + colpos[256 + c];
        const float ca = colall[c] + colall[256 + c];
        ppos[(size_t)I * N_ROWS + col0 + c] = cp;
        pall[(size_t)I * N_ROWS + col0 + c] = ca;
    }
}

// ---------------- Kernel 3a: per-row loss, per-block partial sums ----------------
__global__ __launch_bounds__(256)
void finalize1_kernel(const int* __restrict__ labels, const float* __restrict__ ppos,
                      const float* __restrict__ pall, float* __restrict__ bsum,
                      int* __restrict__ bcnt) {
    __shared__ int hist[NUM_CLS];
    __shared__ float sred[4];
    __shared__ int scnt[4];
    const int tid = threadIdx.x;
    if (tid < NUM_CLS) hist[tid] = 0;
    __syncthreads();
    for (int i = tid; i < N_ROWS; i += 256) atomicAdd(&hist[labels[i]], 1);
    __syncthreads();

    const int i = blockIdx.x * 256 + tid;
    float p = 0.f, a = 0.f;
#pragma unroll
    for (int s = 0; s < NP; ++s) {
        p += ppos[(size_t)s * N_ROWS + i];
        a += pall[(size_t)s * N_ROWS + i];
    }
    float lsum = 0.f;
    int vcnt = 0;
    const int cnt = hist[labels[i]] - 1;
    if (cnt > 0) {
        lsum = logf(a) - logf(p) + logf((float)cnt);
        vcnt = 1;
    }
    const int lane = tid & 63, wid = tid >> 6;
#pragma unroll
    for (int d = 1; d < 64; d <<= 1) {
        lsum += __shfl_xor(lsum, d, 64);
        vcnt += __shfl_xor(vcnt, d, 64);
    }
    if (lane == 0) { sred[wid] = lsum; scnt[wid] = vcnt; }
    __syncthreads();
    if (tid == 0) {
        bsum[blockIdx.x] = sred[0] + sred[1] + sred[2] + sred[3];
        bcnt[blockIdx.x] = scnt[0] + scnt[1] + scnt[2] + scnt[3];
    }
}

// ---------------- Kernel 3b: final scalar ----------------
__global__ __launch_bounds__(64)
void finalize2_kernel(const float* __restrict__ bsum, const int* __restrict__ bcnt,
                      float* __restrict__ out) {
    const int tid = threadIdx.x;
    float s = (tid < NP) ? bsum[tid] : 0.f;
    int   c = (tid < NP) ? bcnt[tid] : 0;
#pragma unroll
    for (int d = 1; d < 64; d <<= 1) {
        s += __shfl_xor(s, d, 64);
        c += __shfl_xor(c, d, 64);
    }
    if (tid == 0) out[0] = s / (float)c;
}

extern "C" void kernel_launch(void* const* d_in, const int* in_sizes, int n_in,
                              void* d_out, int out_size, void* d_ws, size_t ws_size,
                              hipStream_t stream) {
    const float* emb   = (const float*)d_in[0];
    const int* labels  = (const int*)d_in[1];
    float* out         = (float*)d_out;
    char* ws           = (char*)d_ws;

    ushort* xb  = (ushort*)ws;                                   // 16 MB bf16 normalized
    float* ppos = (float*)(ws + (size_t)N_ROWS * H_DIM * 2);     // NP*N floats (1 MB)
    float* pall = ppos + (size_t)NP * N_ROWS;                    // NP*N floats (1 MB)
    float* bsum = pall + (size_t)NP * N_ROWS;                    // 32 floats
    int*   bcnt = (int*)(bsum + NP);                             // 32 ints

    norm_kernel<<<N_ROWS, 256, 0, stream>>>(emb, xb);
    simloss_kernel<<<NPAIR, 512, 0, stream>>>(xb, labels, ppos, pall);
    finalize1_kernel<<<NP, 256, 0, stream>>>(labels, ppos, pall, bsum, bcnt);
    finalize2_kernel<<<1, 64, 0, stream>>>(bsum, bcnt, out);
}

// Round 6
// 116.805 us; speedup vs baseline: 1.2931x; 1.2931x over previous
//
#include <hip/hip_runtime.h>
#include <hip/hip_bf16.h>

#define N_ROWS 8192
#define H_DIM  1024
#define NUM_CLS 64
#define BM 128
#define BN 128
#define BK 128                           // K per step (one scaled MFMA)
#define NBLK (N_ROWS / BM)               // 64 panels
#define NPAIR (NBLK * (NBLK + 1) / 2)    // 2080 upper-triangle blocks
#define SCALE_E8M0 0x7B7B7B7B            // 123 -> 2^-4 per operand (x stored *16)

typedef float f32x4 __attribute__((ext_vector_type(4)));
typedef int   i32x4 __attribute__((ext_vector_type(4)));
typedef int   i32x8 __attribute__((ext_vector_type(8)));

__device__ __forceinline__ float fast_exp2(float x) {
    float r;
    asm("v_exp_f32 %0, %1" : "=v"(r) : "v"(x));
    return r;
}

__device__ __forceinline__ void async_copy16(void* lds, const void* g) {
    __builtin_amdgcn_global_load_lds(
        (const __attribute__((address_space(1))) void*)g,
        (__attribute__((address_space(3))) void*)lds, 16, 0, 0);
}

// ------------- Kernel 1: row-normalize fp32 -> fp8 e4m3 (x * 16) -------------
__global__ __launch_bounds__(256) void norm_kernel(const float* __restrict__ in,
                                                   int* __restrict__ out) {
    const int row = blockIdx.x, tid = threadIdx.x;
    const float4 v = reinterpret_cast<const float4*>(in + (size_t)row * H_DIM)[tid];
    float ss = v.x * v.x + v.y * v.y + v.z * v.z + v.w * v.w;
#pragma unroll
    for (int d = 1; d < 64; d <<= 1) ss += __shfl_xor(ss, d, 64);
    __shared__ float sred[4];
    const int lane = tid & 63, wid = tid >> 6;
    if (lane == 0) sred[wid] = ss;
    __syncthreads();
    const float tot = sred[0] + sred[1] + sred[2] + sred[3];
    const float inv = 16.0f / fmaxf(sqrtf(tot), 1e-12f);   // *16: use e4m3 normal range
    int d = 0;
    d = __builtin_amdgcn_cvt_pk_fp8_f32(v.x * inv, v.y * inv, d, false); // bytes 0,1
    d = __builtin_amdgcn_cvt_pk_fp8_f32(v.z * inv, v.w * inv, d, true);  // bytes 2,3
    out[(size_t)row * (H_DIM / 4) + tid] = d;
}

// ---- Kernel 2: symmetric fused Gram + exp + masked row/col partials ----
// R2-proven structure, MX-fp8: 128x128 tile, 4 waves (2x2), single-buffer
// 32 KB LDS, BK=128, one mfma_scale_f32_16x16x128_f8f6f4 per fragment pair.
__global__ __launch_bounds__(256, 2)
void simloss_kernel(const unsigned char* __restrict__ xq, const int* __restrict__ labels,
                    float* __restrict__ ppos, float* __restrict__ pall) {
    __shared__ __align__(16) unsigned char As[BM * BK];   // 16 KB
    __shared__ __align__(16) unsigned char Bs[BN * BK];   // 16 KB

    // decode linear bid -> (I, J) with I <= J, row-major over the triangle
    int t = blockIdx.x, I = 0;
    while (t >= NBLK - I) { t -= NBLK - I; ++I; }
    const int J = I + t;
    const bool diag = (I == J);
    const int row0 = I * BM, col0 = J * BN;

    const int tid  = threadIdx.x;
    const int lane = tid & 63;
    const int wid  = tid >> 6;
    const int wr = wid >> 1, wc = wid & 1;
    const int l15 = lane & 15, lq = lane >> 4;
    const int l7 = l15 & 7;

    // staging geometry: segment = 1 KB = 8 rows x 128 B; 16 segs per tile;
    // each wave stages 4 segs per tile (A and B) -> 8 issues/thread/K-step
    const int srow  = lane >> 3;   // row within segment (0..7)
    const int pslot = lane & 7;    // physical 16B slot within row (8 slots/row)

    // labels for the 16 rows this lane accumulates
    int lab_r[16];
#pragma unroll
    for (int m = 0; m < 4; ++m)
#pragma unroll
        for (int r = 0; r < 4; ++r)
            lab_r[m * 4 + r] = labels[row0 + wr * 64 + m * 16 + lq * 4 + r];

    f32x4 acc[4][4];
#pragma unroll
    for (int m = 0; m < 4; ++m)
#pragma unroll
        for (int n = 0; n < 4; ++n) acc[m][n] = (f32x4){0.f, 0.f, 0.f, 0.f};

    // fragment read offsets: lane reads 32 B (K = lq*32..+32) of its row,
    // as two 16B slots (2lq, 2lq+1), each XOR-swizzled with row&7 (rule #21)
    const int s0 = ((2 * lq)     ^ l7) * 16;
    const int s1 = ((2 * lq + 1) ^ l7) * 16;

    for (int k0 = 0; k0 < H_DIM; k0 += BK) {
        __syncthreads();   // previous step's LDS reads complete
#pragma unroll
        for (int i = 0; i < 4; ++i) {
            const int seg = wid * 4 + i;
            const int row = seg * 8 + srow;
            const int ls  = pslot ^ (row & 7);   // pre-swizzled source (rule #21)
            async_copy16(&As[seg * 1024],
                         &xq[(size_t)(row0 + row) * H_DIM + k0 + ls * 16]);
            async_copy16(&Bs[seg * 1024],
                         &xq[(size_t)(col0 + row) * H_DIM + k0 + ls * 16]);
        }
        __syncthreads();   // compiler drains vmcnt before s_barrier

        i32x8 av[4], bv[4];
#pragma unroll
        for (int m = 0; m < 4; ++m) {
            const int base = (wr * 64 + m * 16 + l15) * BK;
            const i32x4 lo = *reinterpret_cast<const i32x4*>(&As[base + s0]);
            const i32x4 hi = *reinterpret_cast<const i32x4*>(&As[base + s1]);
            av[m] = __builtin_shufflevector(lo, hi, 0, 1, 2, 3, 4, 5, 6, 7);
        }
#pragma unroll
        for (int n = 0; n < 4; ++n) {
            const int base = (wc * 64 + n * 16 + l15) * BK;
            const i32x4 lo = *reinterpret_cast<const i32x4*>(&Bs[base + s0]);
            const i32x4 hi = *reinterpret_cast<const i32x4*>(&Bs[base + s1]);
            bv[n] = __builtin_shufflevector(lo, hi, 0, 1, 2, 3, 4, 5, 6, 7);
        }
#pragma unroll
        for (int m = 0; m < 4; ++m)
#pragma unroll
            for (int n = 0; n < 4; ++n)
                acc[m][n] = __builtin_amdgcn_mfma_scale_f32_16x16x128_f8f6f4(
                    av[m], bv[n], acc[m][n],
                    0 /*cbsz: fp8 e4m3*/, 0 /*blgp: fp8 e4m3*/,
                    0, SCALE_E8M0, 0, SCALE_E8M0);
    }

    // ---- epilogue: exp + masked row sums AND column sums (unchanged) ----
    float rs_pos[16], rs_all[16];
#pragma unroll
    for (int i = 0; i < 16; ++i) { rs_pos[i] = 0.f; rs_all[i] = 0.f; }
    float cs_pos[4], cs_all[4];
#pragma unroll
    for (int n = 0; n < 4; ++n) { cs_pos[n] = 0.f; cs_all[n] = 0.f; }

#pragma unroll
    for (int n = 0; n < 4; ++n) {
        const int colg = col0 + wc * 64 + n * 16 + l15;
        const int lab_c = labels[colg];
#pragma unroll
        for (int m = 0; m < 4; ++m) {
#pragma unroll
            for (int r = 0; r < 4; ++r) {
                const int rowg = row0 + wr * 64 + m * 16 + lq * 4 + r;
                const float e = fast_exp2(acc[m][n][r] * 14.4269504088896340736f);
                const bool self = (rowg == colg);       // only possible when diag
                const bool pos  = (lab_c == lab_r[m * 4 + r]) && !self;
                const float ea = self ? 0.f : e;
                const float ep = pos ? e : 0.f;
                rs_all[m * 4 + r] += ea;
                rs_pos[m * 4 + r] += ep;
                cs_all[n] += ea;
                cs_pos[n] += ep;
            }
        }
    }

    // row partials: reduce across l15 (16-lane groups)
#pragma unroll
    for (int i = 0; i < 16; ++i) {
#pragma unroll
        for (int d = 1; d < 16; d <<= 1) {
            rs_pos[i] += __shfl_xor(rs_pos[i], d, 64);
            rs_all[i] += __shfl_xor(rs_all[i], d, 64);
        }
    }
    // col partials: reduce across lq (lanes differing in bits 4,5)
#pragma unroll
    for (int n = 0; n < 4; ++n) {
#pragma unroll
        for (int d = 16; d < 64; d <<= 1) {
            cs_pos[n] += __shfl_xor(cs_pos[n], d, 64);
            cs_all[n] += __shfl_xor(cs_all[n], d, 64);
        }
    }

    // cross-wave combine via LDS scratch aliased onto As (4 KB of 16 KB)
    __syncthreads();                       // all LDS fragment reads done
    float* sc = (float*)&As[0];
    float* rowpos = sc;                    // [2][128] indexed [wc][localrow]
    float* rowall = sc + 256;
    float* colpos = sc + 512;              // [2][128] indexed [wr][localcol]
    float* colall = sc + 768;
    if (l15 == 0) {
#pragma unroll
        for (int i = 0; i < 16; ++i) {
            const int m = i >> 2, r = i & 3;
            const int lr = wr * 64 + m * 16 + lq * 4 + r;
            rowpos[wc * 128 + lr] = rs_pos[i];
            rowall[wc * 128 + lr] = rs_all[i];
        }
    }
    if (lq == 0 && !diag) {
#pragma unroll
        for (int n = 0; n < 4; ++n) {
            const int lc = wc * 64 + n * 16 + l15;
            colpos[wr * 128 + lc] = cs_pos[n];
            colall[wr * 128 + lc] = cs_all[n];
        }
    }
    __syncthreads();

    // partial-slot scheme: row-side -> slot J, col-side -> slot I.
    // Every (slot s, row i) written exactly once across the triangle.
    if (tid < 128) {
        const float rp = rowpos[tid] + rowpos[128 + tid];
        const float ra = rowall[tid] + rowall[128 + tid];
        ppos[(size_t)J * N_ROWS + row0 + tid] = rp;
        pall[(size_t)J * N_ROWS + row0 + tid] = ra;
    } else if (!diag) {
        const int t2 = tid - 128;
        const float cp = colpos[t2] + colpos[128 + t2];
        const float ca = colall[t2] + colall[128 + t2];
        ppos[(size_t)I * N_ROWS + col0 + t2] = cp;
        pall[(size_t)I * N_ROWS + col0 + t2] = ca;
    }
}

// ---------------- Kernel 3a: per-row loss, per-block partial sums ----------------
__global__ __launch_bounds__(256)
void finalize1_kernel(const int* __restrict__ labels, const float* __restrict__ ppos,
                      const float* __restrict__ pall, float* __restrict__ bsum,
                      int* __restrict__ bcnt) {
    __shared__ int hist[NUM_CLS];
    __shared__ float sred[4];
    __shared__ int scnt[4];
    const int tid = threadIdx.x;
    if (tid < NUM_CLS) hist[tid] = 0;
    __syncthreads();
    for (int i = tid; i < N_ROWS; i += 256) atomicAdd(&hist[labels[i]], 1);
    __syncthreads();

    float lsum = 0.f;
    int vcnt = 0;
    if (tid < 128) {
        const int i = blockIdx.x * 128 + tid;
        float p = 0.f, a = 0.f;
#pragma unroll
        for (int s = 0; s < NBLK; ++s) {
            p += ppos[(size_t)s * N_ROWS + i];
            a += pall[(size_t)s * N_ROWS + i];
        }
        const int cnt = hist[labels[i]] - 1;
        if (cnt > 0) {
            lsum = logf(a) - logf(p) + logf((float)cnt);
            vcnt = 1;
        }
    }
    const int lane = tid & 63, wid = tid >> 6;
#pragma unroll
    for (int d = 1; d < 64; d <<= 1) {
        lsum += __shfl_xor(lsum, d, 64);
        vcnt += __shfl_xor(vcnt, d, 64);
    }
    if (lane == 0) { sred[wid] = lsum; scnt[wid] = vcnt; }
    __syncthreads();
    if (tid == 0) {
        bsum[blockIdx.x] = sred[0] + sred[1] + sred[2] + sred[3];
        bcnt[blockIdx.x] = scnt[0] + scnt[1] + scnt[2] + scnt[3];
    }
}

// ---------------- Kernel 3b: final scalar ----------------
__global__ __launch_bounds__(64)
void finalize2_kernel(const float* __restrict__ bsum, const int* __restrict__ bcnt,
                      float* __restrict__ out) {
    const int tid = threadIdx.x;
    float s = bsum[tid];
    int   c = bcnt[tid];
#pragma unroll
    for (int d = 1; d < 64; d <<= 1) {
        s += __shfl_xor(s, d, 64);
        c += __shfl_xor(c, d, 64);
    }
    if (tid == 0) out[0] = s / (float)c;
}

extern "C" void kernel_launch(void* const* d_in, const int* in_sizes, int n_in,
                              void* d_out, int out_size, void* d_ws, size_t ws_size,
                              hipStream_t stream) {
    const float* emb   = (const float*)d_in[0];
    const int* labels  = (const int*)d_in[1];
    float* out         = (float*)d_out;
    char* ws           = (char*)d_ws;

    unsigned char* xq = (unsigned char*)ws;                      // 8 MB fp8 (x*16)
    float* ppos = (float*)(ws + (size_t)N_ROWS * H_DIM);         // NBLK*N floats (2 MB)
    float* pall = ppos + (size_t)NBLK * N_ROWS;                  // NBLK*N floats (2 MB)
    float* bsum = pall + (size_t)NBLK * N_ROWS;                  // 64 floats
    int*   bcnt = (int*)(bsum + NBLK);                           // 64 ints

    norm_kernel<<<N_ROWS, 256, 0, stream>>>(emb, (int*)xq);
    simloss_kernel<<<NPAIR, 256, 0, stream>>>(xq, labels, ppos, pall);
    finalize1_kernel<<<NBLK, 256, 0, stream>>>(labels, ppos, pall, bsum, bcnt);
    finalize2_kernel<<<1, 64, 0, stream>>>(bsum, bcnt, out);
}

// Round 7
// 111.603 us; speedup vs baseline: 1.3533x; 1.0466x over previous
//
#include <hip/hip_runtime.h>
#include <hip/hip_bf16.h>

#define N_ROWS 8192
#define H_DIM  1024
#define NUM_CLS 64
#define BM 128
#define BN 128
#define BK 128                           // K per step (one scaled MFMA)
#define NBLK (N_ROWS / BM)               // 64 panels
#define NPAIR (NBLK * (NBLK + 1) / 2)    // 2080 upper-triangle blocks
#define SCALE_E8M0 0x7B7B7B7B            // 123 -> 2^-4 per operand (x stored *16)
#define FIXSCALE 16777216.0              // 2^24 fixed-point for deterministic sum

typedef float f32x4 __attribute__((ext_vector_type(4)));
typedef int   i32x4 __attribute__((ext_vector_type(4)));
typedef int   i32x8 __attribute__((ext_vector_type(8)));

__device__ __forceinline__ float fast_exp2(float x) {
    float r;
    asm("v_exp_f32 %0, %1" : "=v"(r) : "v"(x));
    return r;
}

__device__ __forceinline__ void async_copy16(void* lds, const void* g) {
    __builtin_amdgcn_global_load_lds(
        (const __attribute__((address_space(1))) void*)g,
        (__attribute__((address_space(3))) void*)lds, 16, 0, 0);
}

// ------- Kernel 1: row-normalize fp32 -> fp8 e4m3 (x*16); 4 rows/block -------
__global__ __launch_bounds__(256) void norm_kernel(const float* __restrict__ in,
                                                   int* __restrict__ out,
                                                   unsigned long long* __restrict__ acc) {
    if (blockIdx.x == 0 && threadIdx.x < 4) acc[threadIdx.x] = 0ULL;  // zero reducers
    const int row  = blockIdx.x * 4 + (threadIdx.x >> 6);
    const int lane = threadIdx.x & 63;
    const float4* src = reinterpret_cast<const float4*>(in + (size_t)row * H_DIM);
    float4 v[4];
    float ss = 0.f;
#pragma unroll
    for (int i = 0; i < 4; ++i) {
        v[i] = src[i * 64 + lane];                    // coalesced 16B/lane
        ss += v[i].x * v[i].x + v[i].y * v[i].y + v[i].z * v[i].z + v[i].w * v[i].w;
    }
#pragma unroll
    for (int d = 1; d < 64; d <<= 1) ss += __shfl_xor(ss, d, 64);
    const float inv = 16.0f / fmaxf(sqrtf(ss), 1e-12f);   // *16: e4m3 normal range
    int* op = out + (size_t)row * (H_DIM / 4);
#pragma unroll
    for (int i = 0; i < 4; ++i) {
        int d = 0;
        d = __builtin_amdgcn_cvt_pk_fp8_f32(v[i].x * inv, v[i].y * inv, d, false);
        d = __builtin_amdgcn_cvt_pk_fp8_f32(v[i].z * inv, v[i].w * inv, d, true);
        op[i * 64 + lane] = d;
    }
}

// ---- Kernel 2: symmetric fused Gram + exp + masked row/col partials ----
// R2-proven structure, MX-fp8, XCD-chunked block swizzle, R2 slot families
// via K-storage permutation: physical slot p holds logical K-chunk
// ((p&3)<<1)|(p>>2), so reads use slots {lq^l7} and {(4+lq)^l7}.
__global__ __launch_bounds__(256, 2)
void simloss_kernel(const unsigned char* __restrict__ xq, const int* __restrict__ labels,
                    float* __restrict__ ppos, float* __restrict__ pall) {
    __shared__ __align__(16) unsigned char As[BM * BK];   // 16 KB
    __shared__ __align__(16) unsigned char Bs[BN * BK];   // 16 KB

    // T1: XCD-chunked swizzle (2080 = 8*260, exact) -> contiguous I-runs/XCD
    const int bid = (blockIdx.x & 7) * (NPAIR / 8) + (blockIdx.x >> 3);
    // decode linear bid -> (I, J) with I <= J, row-major over the triangle
    int t = bid, I = 0;
    while (t >= NBLK - I) { t -= NBLK - I; ++I; }
    const int J = I + t;
    const bool diag = (I == J);
    const int row0 = I * BM, col0 = J * BN;

    const int tid  = threadIdx.x;
    const int lane = tid & 63;
    const int wid  = tid >> 6;
    const int wr = wid >> 1, wc = wid & 1;
    const int l15 = lane & 15, lq = lane >> 4;
    const int l7 = l15 & 7;

    // staging geometry: segment = 1 KB = 8 rows x 128 B; 16 segs per tile
    const int srow  = lane >> 3;   // row within segment (0..7)
    const int pslot = lane & 7;    // physical 16B slot within row

    int lab_r[16];
#pragma unroll
    for (int m = 0; m < 4; ++m)
#pragma unroll
        for (int r = 0; r < 4; ++r)
            lab_r[m * 4 + r] = labels[row0 + wr * 64 + m * 16 + lq * 4 + r];

    f32x4 acc[4][4];
#pragma unroll
    for (int m = 0; m < 4; ++m)
#pragma unroll
        for (int n = 0; n < 4; ++n) acc[m][n] = (f32x4){0.f, 0.f, 0.f, 0.f};

    // fragment reads: lane needs K [lq*32, +32) = logical chunks 2lq, 2lq+1,
    // stored at physical slots lq^row7 and (4+lq)^row7 (R2's zero-conflict families)
    const int s0 = (lq ^ l7) * 16;
    const int s1 = ((4 + lq) ^ l7) * 16;

    for (int k0 = 0; k0 < H_DIM; k0 += BK) {
        __syncthreads();   // previous step's LDS reads complete
#pragma unroll
        for (int i = 0; i < 4; ++i) {
            const int seg = wid * 4 + i;
            const int row = seg * 8 + srow;
            const int p   = pslot ^ (row & 7);            // logical slot position
            const int ls  = ((p & 3) << 1) | (p >> 2);    // logical K-chunk stored here
            async_copy16(&As[seg * 1024],
                         &xq[(size_t)(row0 + row) * H_DIM + k0 + ls * 16]);
            async_copy16(&Bs[seg * 1024],
                         &xq[(size_t)(col0 + row) * H_DIM + k0 + ls * 16]);
        }
        __syncthreads();   // compiler drains vmcnt before s_barrier

        i32x8 av[4], bv[4];
#pragma unroll
        for (int m = 0; m < 4; ++m) {
            const int base = (wr * 64 + m * 16 + l15) * BK;
            const i32x4 lo = *reinterpret_cast<const i32x4*>(&As[base + s0]);
            const i32x4 hi = *reinterpret_cast<const i32x4*>(&As[base + s1]);
            av[m] = __builtin_shufflevector(lo, hi, 0, 1, 2, 3, 4, 5, 6, 7);
        }
#pragma unroll
        for (int n = 0; n < 4; ++n) {
            const int base = (wc * 64 + n * 16 + l15) * BK;
            const i32x4 lo = *reinterpret_cast<const i32x4*>(&Bs[base + s0]);
            const i32x4 hi = *reinterpret_cast<const i32x4*>(&Bs[base + s1]);
            bv[n] = __builtin_shufflevector(lo, hi, 0, 1, 2, 3, 4, 5, 6, 7);
        }
#pragma unroll
        for (int m = 0; m < 4; ++m)
#pragma unroll
            for (int n = 0; n < 4; ++n)
                acc[m][n] = __builtin_amdgcn_mfma_scale_f32_16x16x128_f8f6f4(
                    av[m], bv[n], acc[m][n],
                    0 /*cbsz: fp8 e4m3*/, 0 /*blgp: fp8 e4m3*/,
                    0, SCALE_E8M0, 0, SCALE_E8M0);
    }

    // ---- epilogue: exp + masked row sums AND column sums ----
    float rs_pos[16], rs_all[16];
#pragma unroll
    for (int i = 0; i < 16; ++i) { rs_pos[i] = 0.f; rs_all[i] = 0.f; }
    float cs_pos[4], cs_all[4];
#pragma unroll
    for (int n = 0; n < 4; ++n) { cs_pos[n] = 0.f; cs_all[n] = 0.f; }

#pragma unroll
    for (int n = 0; n < 4; ++n) {
        const int colg = col0 + wc * 64 + n * 16 + l15;
        const int lab_c = labels[colg];
#pragma unroll
        for (int m = 0; m < 4; ++m) {
#pragma unroll
            for (int r = 0; r < 4; ++r) {
                const int rowg = row0 + wr * 64 + m * 16 + lq * 4 + r;
                const float e = fast_exp2(acc[m][n][r] * 14.4269504088896340736f);
                const bool self = (rowg == colg);       // only possible when diag
                const bool pos  = (lab_c == lab_r[m * 4 + r]) && !self;
                const float ea = self ? 0.f : e;
                const float ep = pos ? e : 0.f;
                rs_all[m * 4 + r] += ea;
                rs_pos[m * 4 + r] += ep;
                cs_all[n] += ea;
                cs_pos[n] += ep;
            }
        }
    }

#pragma unroll
    for (int i = 0; i < 16; ++i) {
#pragma unroll
        for (int d = 1; d < 16; d <<= 1) {
            rs_pos[i] += __shfl_xor(rs_pos[i], d, 64);
            rs_all[i] += __shfl_xor(rs_all[i], d, 64);
        }
    }
#pragma unroll
    for (int n = 0; n < 4; ++n) {
#pragma unroll
        for (int d = 16; d < 64; d <<= 1) {
            cs_pos[n] += __shfl_xor(cs_pos[n], d, 64);
            cs_all[n] += __shfl_xor(cs_all[n], d, 64);
        }
    }

    __syncthreads();                       // all LDS fragment reads done
    float* sc = (float*)&As[0];
    float* rowpos = sc;                    // [2][128] indexed [wc][localrow]
    float* rowall = sc + 256;
    float* colpos = sc + 512;              // [2][128] indexed [wr][localcol]
    float* colall = sc + 768;
    if (l15 == 0) {
#pragma unroll
        for (int i = 0; i < 16; ++i) {
            const int m = i >> 2, r = i & 3;
            const int lr = wr * 64 + m * 16 + lq * 4 + r;
            rowpos[wc * 128 + lr] = rs_pos[i];
            rowall[wc * 128 + lr] = rs_all[i];
        }
    }
    if (lq == 0 && !diag) {
#pragma unroll
        for (int n = 0; n < 4; ++n) {
            const int lc = wc * 64 + n * 16 + l15;
            colpos[wr * 128 + lc] = cs_pos[n];
            colall[wr * 128 + lc] = cs_all[n];
        }
    }
    __syncthreads();

    // partial-slot scheme: row-side -> slot J, col-side -> slot I (exactly once)
    if (tid < 128) {
        const float rp = rowpos[tid] + rowpos[128 + tid];
        const float ra = rowall[tid] + rowall[128 + tid];
        ppos[(size_t)J * N_ROWS + row0 + tid] = rp;
        pall[(size_t)J * N_ROWS + row0 + tid] = ra;
    } else if (!diag) {
        const int t2 = tid - 128;
        const float cp = colpos[t2] + colpos[128 + t2];
        const float ca = colall[t2] + colall[128 + t2];
        ppos[(size_t)I * N_ROWS + col0 + t2] = cp;
        pall[(size_t)I * N_ROWS + col0 + t2] = ca;
    }
}

// ---- Kernel 3: fused finalize (deterministic int64 fixed-point + ticket) ----
__global__ __launch_bounds__(256)
void finalize_kernel(const int* __restrict__ labels, const float* __restrict__ ppos,
                     const float* __restrict__ pall, unsigned long long* __restrict__ acc,
                     float* __restrict__ out) {
    __shared__ int hist[NUM_CLS];
    __shared__ float sred[4];
    __shared__ int scnt[4];
    const int tid = threadIdx.x;
    if (tid < NUM_CLS) hist[tid] = 0;
    __syncthreads();
    for (int i = tid; i < N_ROWS; i += 256) atomicAdd(&hist[labels[i]], 1);
    __syncthreads();

    float lsum = 0.f;
    int vcnt = 0;
    if (tid < 128) {
        const int i = blockIdx.x * 128 + tid;
        float p = 0.f, a = 0.f;
#pragma unroll
        for (int s = 0; s < NBLK; ++s) {
            p += ppos[(size_t)s * N_ROWS + i];
            a += pall[(size_t)s * N_ROWS + i];
        }
        const int cnt = hist[labels[i]] - 1;
        if (cnt > 0) {
            lsum = logf(a) - logf(p) + logf((float)cnt);   // >= 0 structurally
            vcnt = 1;
        }
    }
    const int lane = tid & 63, wid = tid >> 6;
#pragma unroll
    for (int d = 1; d < 64; d <<= 1) {
        lsum += __shfl_xor(lsum, d, 64);
        vcnt += __shfl_xor(vcnt, d, 64);
    }
    if (lane == 0) { sred[wid] = lsum; scnt[wid] = vcnt; }
    __syncthreads();
    if (tid == 0) {
        const double bs = (double)(sred[0] + sred[1] + sred[2] + sred[3]);
        const unsigned long long S = (unsigned long long)(bs * FIXSCALE + 0.5);
        const unsigned long long C = (unsigned long long)(scnt[0] + scnt[1] + scnt[2] + scnt[3]);
        atomicAdd(&acc[1], S);
        atomicAdd(&acc[2], C);
        __threadfence();
        const unsigned long long tk = atomicAdd(&acc[0], 1ULL);
        if (tk == (unsigned long long)(NBLK - 1)) {
            volatile unsigned long long* va = acc;
            const double St = (double)va[1];
            const double Ct = (double)va[2];
            out[0] = (float)(St / FIXSCALE / Ct);
        }
    }
}

extern "C" void kernel_launch(void* const* d_in, const int* in_sizes, int n_in,
                              void* d_out, int out_size, void* d_ws, size_t ws_size,
                              hipStream_t stream) {
    const float* emb   = (const float*)d_in[0];
    const int* labels  = (const int*)d_in[1];
    float* out         = (float*)d_out;
    char* ws           = (char*)d_ws;

    unsigned char* xq = (unsigned char*)ws;                      // 8 MB fp8 (x*16)
    float* ppos = (float*)(ws + (size_t)N_ROWS * H_DIM);         // NBLK*N floats (2 MB)
    float* pall = ppos + (size_t)NBLK * N_ROWS;                  // NBLK*N floats (2 MB)
    unsigned long long* acc = (unsigned long long*)(pall + (size_t)NBLK * N_ROWS);

    norm_kernel<<<N_ROWS / 4, 256, 0, stream>>>(emb, (int*)xq, acc);
    simloss_kernel<<<NPAIR, 256, 0, stream>>>(xq, labels, ppos, pall);
    finalize_kernel<<<NBLK, 256, 0, stream>>>(labels, ppos, pall, acc, out);
}

// Round 8
// 108.356 us; speedup vs baseline: 1.3939x; 1.0300x over previous
//
#include <hip/hip_runtime.h>
#include <hip/hip_bf16.h>

#define N_ROWS 8192
#define H_DIM  1024
#define NUM_CLS 64
#define BM 128
#define BN 128
#define BK 128                           // K per step (one scaled MFMA)
#define NBLK (N_ROWS / BM)               // 64 panels
#define SCALE_E8M0 0x7B7B7B7B            // 123 -> 2^-4 per operand (x stored *16)
#define FIXSCALE 16777216.0              // 2^24 fixed-point for deterministic sum
#define GRID_K2 (8 * 264)                // 8 XCD slots x 264 (32 no-op blocks)

typedef float f32x4 __attribute__((ext_vector_type(4)));
typedef int   i32x4 __attribute__((ext_vector_type(4)));
typedef int   i32x8 __attribute__((ext_vector_type(8)));

__device__ __forceinline__ float fast_exp2(float x) {
    float r;
    asm("v_exp_f32 %0, %1" : "=v"(r) : "v"(x));
    return r;
}

__device__ __forceinline__ void async_copy16(void* lds, const void* g) {
    __builtin_amdgcn_global_load_lds(
        (const __attribute__((address_space(1))) void*)g,
        (__attribute__((address_space(3))) void*)lds, 16, 0, 0);
}

// ------- Kernel 1: row-normalize fp32 -> fp8 e4m3 (x*16); 4 rows/block -------
__global__ __launch_bounds__(256) void norm_kernel(const float* __restrict__ in,
                                                   int* __restrict__ out,
                                                   unsigned long long* __restrict__ acc) {
    if (blockIdx.x == 0 && threadIdx.x < 4) acc[threadIdx.x] = 0ULL;  // zero reducers
    const int row  = blockIdx.x * 4 + (threadIdx.x >> 6);
    const int lane = threadIdx.x & 63;
    const float4* src = reinterpret_cast<const float4*>(in + (size_t)row * H_DIM);
    float4 v[4];
    float ss = 0.f;
#pragma unroll
    for (int i = 0; i < 4; ++i) {
        v[i] = src[i * 64 + lane];                    // coalesced 16B/lane
        ss += v[i].x * v[i].x + v[i].y * v[i].y + v[i].z * v[i].z + v[i].w * v[i].w;
    }
#pragma unroll
    for (int d = 1; d < 64; d <<= 1) ss += __shfl_xor(ss, d, 64);
    const float inv = 16.0f / fmaxf(sqrtf(ss), 1e-12f);   // *16: e4m3 normal range
    int* op = out + (size_t)row * (H_DIM / 4);
#pragma unroll
    for (int i = 0; i < 4; ++i) {
        int d = 0;
        d = __builtin_amdgcn_cvt_pk_fp8_f32(v[i].x * inv, v[i].y * inv, d, false);
        d = __builtin_amdgcn_cvt_pk_fp8_f32(v[i].z * inv, v[i].w * inv, d, true);
        op[i * 64 + lane] = d;
    }
}

// 28 off-diagonal 8x8-panel super-tiles (a<b), packed a<<3|b, row-major
__device__ __constant__ unsigned char OFF_TBL[28] = {
    1, 2, 3, 4, 5, 6, 7,            // (0,1)..(0,7)
    10, 11, 12, 13, 14, 15,         // (1,2)..(1,7)
    19, 20, 21, 22, 23,             // (2,3)..(2,7)
    28, 29, 30, 31,                 // (3,4)..(3,7)
    37, 38, 39,                     // (4,5)..(4,7)
    46, 47,                         // (5,6),(5,7)
    55                              // (6,7)
};

// ---- Kernel 2: symmetric fused Gram + exp + masked row/col partials ----
// R7-proven body. New: 8x8-panel super-tile -> XCD co-scheduling (blockIdx%8):
// each XCD works one super-tile at a time; working set 2 MB = L2-resident,
// every staged line shared by ~8 co-resident blocks -> stage drains are L2-hit.
__global__ __launch_bounds__(256, 2)
void simloss_kernel(const unsigned char* __restrict__ xq, const int* __restrict__ labels,
                    float* __restrict__ ppos, float* __restrict__ pall) {
    __shared__ __align__(16) unsigned char As[BM * BK];   // 16 KB
    __shared__ __align__(16) unsigned char Bs[BN * BK];   // 16 KB

    // ---- super-tile decode: xcd = blockIdx%8 owns a fixed tile list ----
    const int xcd = blockIdx.x & 7;
    const int n   = blockIdx.x >> 3;     // 0..263 within this XCD
    int I, J;
    if (xcd < 4) {                        // 4 off-diag tiles (256 blocks)
        if (n >= 256) return;
        const int t = OFF_TBL[xcd * 4 + (n >> 6)];
        I = (t >> 3) * 8 + ((n >> 3) & 7);
        J = (t & 7) * 8 + (n & 7);
    } else if (n < 192) {                 // 3 off-diag tiles
        const int t = OFF_TBL[16 + (xcd - 4) * 3 + (n >> 6)];
        I = (t >> 3) * 8 + ((n >> 3) & 7);
        J = (t & 7) * 8 + (n & 7);
    } else {                              // 2 diag tiles (36 blocks each)
        int n2 = n - 192;                 // 0..71
        const int D = (xcd - 4) * 2 + (n2 >= 36 ? 1 : 0);
        int t2 = (n2 >= 36) ? n2 - 36 : n2;
        int i = 0;
        while (t2 >= 8 - i) { t2 -= 8 - i; ++i; }
        I = D * 8 + i;
        J = D * 8 + i + t2;
    }
    const bool diag = (I == J);
    const int row0 = I * BM, col0 = J * BN;

    const int tid  = threadIdx.x;
    const int lane = tid & 63;
    const int wid  = tid >> 6;
    const int wr = wid >> 1, wc = wid & 1;
    const int l15 = lane & 15, lq = lane >> 4;
    const int l7 = l15 & 7;

    // staging geometry: segment = 1 KB = 8 rows x 128 B; 16 segs per tile
    const int srow  = lane >> 3;   // row within segment (0..7)
    const int pslot = lane & 7;    // physical 16B slot within row

    int lab_r[16];
#pragma unroll
    for (int m = 0; m < 4; ++m)
#pragma unroll
        for (int r = 0; r < 4; ++r)
            lab_r[m * 4 + r] = labels[row0 + wr * 64 + m * 16 + lq * 4 + r];

    f32x4 acc[4][4];
#pragma unroll
    for (int m = 0; m < 4; ++m)
#pragma unroll
        for (int n2 = 0; n2 < 4; ++n2) acc[m][n2] = (f32x4){0.f, 0.f, 0.f, 0.f};

    // fragment reads: lane needs K [lq*32, +32) = logical chunks 2lq, 2lq+1,
    // stored at physical slots lq^row7 and (4+lq)^row7 (zero-conflict families)
    const int s0 = (lq ^ l7) * 16;
    const int s1 = ((4 + lq) ^ l7) * 16;

    for (int k0 = 0; k0 < H_DIM; k0 += BK) {
        __syncthreads();   // previous step's LDS reads complete
#pragma unroll
        for (int i = 0; i < 4; ++i) {
            const int seg = wid * 4 + i;
            const int row = seg * 8 + srow;
            const int p   = pslot ^ (row & 7);            // logical slot position
            const int ls  = ((p & 3) << 1) | (p >> 2);    // logical K-chunk stored here
            async_copy16(&As[seg * 1024],
                         &xq[(size_t)(row0 + row) * H_DIM + k0 + ls * 16]);
            async_copy16(&Bs[seg * 1024],
                         &xq[(size_t)(col0 + row) * H_DIM + k0 + ls * 16]);
        }
        __syncthreads();   // compiler drains vmcnt before s_barrier

        i32x8 av[4], bv[4];
#pragma unroll
        for (int m = 0; m < 4; ++m) {
            const int base = (wr * 64 + m * 16 + l15) * BK;
            const i32x4 lo = *reinterpret_cast<const i32x4*>(&As[base + s0]);
            const i32x4 hi = *reinterpret_cast<const i32x4*>(&As[base + s1]);
            av[m] = __builtin_shufflevector(lo, hi, 0, 1, 2, 3, 4, 5, 6, 7);
        }
#pragma unroll
        for (int n2 = 0; n2 < 4; ++n2) {
            const int base = (wc * 64 + n2 * 16 + l15) * BK;
            const i32x4 lo = *reinterpret_cast<const i32x4*>(&Bs[base + s0]);
            const i32x4 hi = *reinterpret_cast<const i32x4*>(&Bs[base + s1]);
            bv[n2] = __builtin_shufflevector(lo, hi, 0, 1, 2, 3, 4, 5, 6, 7);
        }
#pragma unroll
        for (int m = 0; m < 4; ++m)
#pragma unroll
            for (int n2 = 0; n2 < 4; ++n2)
                acc[m][n2] = __builtin_amdgcn_mfma_scale_f32_16x16x128_f8f6f4(
                    av[m], bv[n2], acc[m][n2],
                    0 /*cbsz: fp8 e4m3*/, 0 /*blgp: fp8 e4m3*/,
                    0, SCALE_E8M0, 0, SCALE_E8M0);
    }

    // ---- epilogue: exp + masked row sums AND column sums ----
    float rs_pos[16], rs_all[16];
#pragma unroll
    for (int i = 0; i < 16; ++i) { rs_pos[i] = 0.f; rs_all[i] = 0.f; }
    float cs_pos[4], cs_all[4];
#pragma unroll
    for (int n2 = 0; n2 < 4; ++n2) { cs_pos[n2] = 0.f; cs_all[n2] = 0.f; }

#pragma unroll
    for (int n2 = 0; n2 < 4; ++n2) {
        const int colg = col0 + wc * 64 + n2 * 16 + l15;
        const int lab_c = labels[colg];
#pragma unroll
        for (int m = 0; m < 4; ++m) {
#pragma unroll
            for (int r = 0; r < 4; ++r) {
                const int rowg = row0 + wr * 64 + m * 16 + lq * 4 + r;
                const float e = fast_exp2(acc[m][n2][r] * 14.4269504088896340736f);
                const bool self = (rowg == colg);       // only possible when diag
                const bool pos  = (lab_c == lab_r[m * 4 + r]) && !self;
                const float ea = self ? 0.f : e;
                const float ep = pos ? e : 0.f;
                rs_all[m * 4 + r] += ea;
                rs_pos[m * 4 + r] += ep;
                cs_all[n2] += ea;
                cs_pos[n2] += ep;
            }
        }
    }

#pragma unroll
    for (int i = 0; i < 16; ++i) {
#pragma unroll
        for (int d = 1; d < 16; d <<= 1) {
            rs_pos[i] += __shfl_xor(rs_pos[i], d, 64);
            rs_all[i] += __shfl_xor(rs_all[i], d, 64);
        }
    }
#pragma unroll
    for (int n2 = 0; n2 < 4; ++n2) {
#pragma unroll
        for (int d = 16; d < 64; d <<= 1) {
            cs_pos[n2] += __shfl_xor(cs_pos[n2], d, 64);
            cs_all[n2] += __shfl_xor(cs_all[n2], d, 64);
        }
    }

    __syncthreads();                       // all LDS fragment reads done
    float* sc = (float*)&As[0];
    float* rowpos = sc;                    // [2][128] indexed [wc][localrow]
    float* rowall = sc + 256;
    float* colpos = sc + 512;              // [2][128] indexed [wr][localcol]
    float* colall = sc + 768;
    if (l15 == 0) {
#pragma unroll
        for (int i = 0; i < 16; ++i) {
            const int m = i >> 2, r = i & 3;
            const int lr = wr * 64 + m * 16 + lq * 4 + r;
            rowpos[wc * 128 + lr] = rs_pos[i];
            rowall[wc * 128 + lr] = rs_all[i];
        }
    }
    if (lq == 0 && !diag) {
#pragma unroll
        for (int n2 = 0; n2 < 4; ++n2) {
            const int lc = wc * 64 + n2 * 16 + l15;
            colpos[wr * 128 + lc] = cs_pos[n2];
            colall[wr * 128 + lc] = cs_all[n2];
        }
    }
    __syncthreads();

    // partial-slot scheme: row-side -> slot J, col-side -> slot I (exactly once)
    if (tid < 128) {
        const float rp = rowpos[tid] + rowpos[128 + tid];
        const float ra = rowall[tid] + rowall[128 + tid];
        ppos[(size_t)J * N_ROWS + row0 + tid] = rp;
        pall[(size_t)J * N_ROWS + row0 + tid] = ra;
    } else if (!diag) {
        const int t2 = tid - 128;
        const float cp = colpos[t2] + colpos[128 + t2];
        const float ca = colall[t2] + colall[128 + t2];
        ppos[(size_t)I * N_ROWS + col0 + t2] = cp;
        pall[(size_t)I * N_ROWS + col0 + t2] = ca;
    }
}

// ---- Kernel 3: fused finalize (deterministic int64 fixed-point + ticket) ----
__global__ __launch_bounds__(256)
void finalize_kernel(const int* __restrict__ labels, const float* __restrict__ ppos,
                     const float* __restrict__ pall, unsigned long long* __restrict__ acc,
                     float* __restrict__ out) {
    __shared__ int hist[NUM_CLS];
    __shared__ float sred[4];
    __shared__ int scnt[4];
    const int tid = threadIdx.x;
    if (tid < NUM_CLS) hist[tid] = 0;
    __syncthreads();
    for (int i = tid; i < N_ROWS; i += 256) atomicAdd(&hist[labels[i]], 1);
    __syncthreads();

    float lsum = 0.f;
    int vcnt = 0;
    if (tid < 128) {
        const int i = blockIdx.x * 128 + tid;
        float p = 0.f, a = 0.f;
#pragma unroll
        for (int s = 0; s < NBLK; ++s) {
            p += ppos[(size_t)s * N_ROWS + i];
            a += pall[(size_t)s * N_ROWS + i];
        }
        const int cnt = hist[labels[i]] - 1;
        if (cnt > 0) {
            lsum = logf(a) - logf(p) + logf((float)cnt);   // >= 0 structurally
            vcnt = 1;
        }
    }
    const int lane = tid & 63, wid = tid >> 6;
#pragma unroll
    for (int d = 1; d < 64; d <<= 1) {
        lsum += __shfl_xor(lsum, d, 64);
        vcnt += __shfl_xor(vcnt, d, 64);
    }
    if (lane == 0) { sred[wid] = lsum; scnt[wid] = vcnt; }
    __syncthreads();
    if (tid == 0) {
        const double bs = (double)(sred[0] + sred[1] + sred[2] + sred[3]);
        const unsigned long long S = (unsigned long long)(bs * FIXSCALE + 0.5);
        const unsigned long long C = (unsigned long long)(scnt[0] + scnt[1] + scnt[2] + scnt[3]);
        atomicAdd(&acc[1], S);
        atomicAdd(&acc[2], C);
        __threadfence();
        const unsigned long long tk = atomicAdd(&acc[0], 1ULL);
        if (tk == (unsigned long long)(NBLK - 1)) {
            volatile unsigned long long* va = acc;
            const double St = (double)va[1];
            const double Ct = (double)va[2];
            out[0] = (float)(St / FIXSCALE / Ct);
        }
    }
}

extern "C" void kernel_launch(void* const* d_in, const int* in_sizes, int n_in,
                              void* d_out, int out_size, void* d_ws, size_t ws_size,
                              hipStream_t stream) {
    const float* emb   = (const float*)d_in[0];
    const int* labels  = (const int*)d_in[1];
    float* out         = (float*)d_out;
    char* ws           = (char*)d_ws;

    unsigned char* xq = (unsigned char*)ws;                      // 8 MB fp8 (x*16)
    float* ppos = (float*)(ws + (size_t)N_ROWS * H_DIM);         // NBLK*N floats (2 MB)
    float* pall = ppos + (size_t)NBLK * N_ROWS;                  // NBLK*N floats (2 MB)
    unsigned long long* acc = (unsigned long long*)(pall + (size_t)NBLK * N_ROWS);

    norm_kernel<<<N_ROWS / 4, 256, 0, stream>>>(emb, (int*)xq, acc);
    simloss_kernel<<<GRID_K2, 256, 0, stream>>>(xq, labels, ppos, pall);
    finalize_kernel<<<NBLK, 256, 0, stream>>>(labels, ppos, pall, acc, out);
}